// Round 2
// baseline (378.889 us; speedup 1.0000x reference)
//
#include <hip/hip_runtime.h>

#define B 256
#define R 2048
#define H 64
#define E 20
#define LN_EPS 1e-5f

#define NB_EDGE 256
#define NB_MAIN 2048
#define TILES_PER_BLOCK 4   // NB_MAIN * TILES_PER_BLOCK * 64 == B*R

typedef float f32x4 __attribute__((ext_vector_type(4)));
typedef short s16x8 __attribute__((ext_vector_type(8)));

__device__ __forceinline__ unsigned short f2bf(float x){
  unsigned int u = __float_as_uint(x);
  u += 0x7fffu + ((u >> 16) & 1u);   // round-to-nearest-even
  return (unsigned short)(u >> 16);
}

__device__ __forceinline__ float wave64_sum(float v){
  #pragma unroll
  for (int m = 1; m < 64; m <<= 1) v += __shfl_xor(v, m, 64);
  return v;
}

// ---------------------------------------------------------------------------
// LDS layouts (union: edge blocks vs main blocks)
// ---------------------------------------------------------------------------
struct MainS {
  unsigned short lw1[H*72];        // W1_top transposed [n][k], bf16, pad 72
  unsigned short lw2[H*72];        // W2 transposed    [n][k], bf16, pad 72
  union {                          // per-wave scratch:
    unsigned short h[16*72];       //   hidden tile (bf16, pad 72)
    float          x[16*68];       //   f32 output transpose (pad 68)
  } scratch[4];
  float lg[4][16];                 // per-wave gate values
  float lc1[H];                    // prompt_zero @ W1_bot + fus_b1
  float lb2[H];
  float lgw[H];                    // gate_W top half
  float lgz;                       // prompt_zero . gate_W_bot + gate_b
};
struct EdgeS {
  float wsum[H*H];                 // msg_W top + bottom halves
  float msgbuf[E][H];
  int   et[E];
};
union SMem { MainS m; EdgeS e; };

// ---------------------------------------------------------------------------
// fused kernel: blocks [0,NB_EDGE) = per-sample prompt encoder (sparse rows),
//               blocks [NB_EDGE, NB_EDGE+NB_MAIN) = dense main path.
// ---------------------------------------------------------------------------
__global__ __launch_bounds__(256) void fused_kernel(
    const int* __restrict__ qrel, const int* __restrict__ etype,
    const float* __restrict__ base, const float* __restrict__ noise,
    const float* __restrict__ msg_W, const float* __restrict__ msg_b,
    const float* __restrict__ upd_W, const float* __restrict__ upd_b,
    const float* __restrict__ ln_g,  const float* __restrict__ ln_b,
    const float* __restrict__ fus_W1,const float* __restrict__ fus_b1,
    const float* __restrict__ fus_W2,const float* __restrict__ fus_b2,
    const float* __restrict__ gate_W,const float* __restrict__ gate_b,
    int* __restrict__ trows, float* __restrict__ tprompt,
    float* __restrict__ out)
{
  __shared__ SMem smem;
  int tid = threadIdx.x;
  int w = tid >> 6, ln = tid & 63;

  if (blockIdx.x < NB_EDGE) {
    // ------------------------------ EDGE PATH ------------------------------
    EdgeS* S = &smem.e;
    int b = blockIdx.x;
    if (tid < E) S->et[tid] = etype[b*E + tid];
    for (int i = tid; i < H*H; i += 256)
      S->wsum[i] = msg_W[i] + msg_W[H*H + i];
    __syncthreads();
    int q = qrel[b];

    // phase B: messages (wave w handles e = w, w+4, ...)
    #pragma unroll
    for (int i = 0; i < E/4; ++i) {
      int e = w + i*4;
      int r = S->et[e];
      float hv = (r == q) ? 1.0f : noise[((size_t)b*R + r)*H + ln] * 0.1f;
      float acc = msg_b[ln];
      #pragma unroll 8
      for (int k = 0; k < H; ++k)
        acc += __shfl(hv, k, 64) * S->wsum[k*H + ln];
      S->msgbuf[e][ln] = fmaxf(acc, 0.f);
    }
    __syncthreads();

    // phase C: dedup + aggregate + update-net + LN
    #pragma unroll
    for (int i = 0; i < E/4; ++i) {
      int e = w + i*4;
      int r = S->et[e];
      bool first = true;
      for (int e2 = 0; e2 < e; ++e2) if (S->et[e2] == r) first = false;
      if (!first) { if (ln == 0) trows[b*E + e] = -1; continue; }
      float agg = 0.f;
      for (int e2 = e; e2 < E; ++e2)
        if (S->et[e2] == r) agg += S->msgbuf[e2][ln];
      float u = upd_b[ln];
      #pragma unroll 8
      for (int k = 0; k < H; ++k)
        u += __shfl(agg, k, 64) * upd_W[k*H + ln];
      float mu = wave64_sum(u) * (1.0f/H);
      float d  = u - mu;
      float var= wave64_sum(d*d) * (1.0f/H);
      float p  = d * rsqrtf(var + LN_EPS) * ln_g[ln] + ln_b[ln];
      tprompt[(b*E + e)*H + ln] = p;
      if (ln == 0) trows[b*E + e] = r;
    }
    return;
  }

  // ------------------------------- MAIN PATH -------------------------------
  MainS* S = &smem.m;
  // stage: coalesced global read, transposed bf16 LDS write
  for (int i = tid; i < H*H; i += 256) {
    int k = i >> 6, n = i & 63;
    S->lw1[n*72 + k] = f2bf(fus_W1[i]);   // top half of fus_W1
    S->lw2[n*72 + k] = f2bf(fus_W2[i]);
  }
  if (tid < H) {
    S->lb2[tid] = fus_b2[tid];
    S->lgw[tid] = gate_W[tid];
  }
  if (tid < 64) {          // wave 0: prompt_zero, c1z, gz
    float u  = upd_b[tid];
    float mu = wave64_sum(u) * (1.0f/H);
    float d  = u - mu;
    float var= wave64_sum(d*d) * (1.0f/H);
    float p  = d * rsqrtf(var + LN_EPS) * ln_g[tid] + ln_b[tid];
    float acc = fus_b1[tid];
    #pragma unroll 8
    for (int k = 0; k < H; ++k)
      acc += __shfl(p, k, 64) * fus_W1[(H+k)*H + tid];
    S->lc1[tid] = acc;
    float gp = p * gate_W[H + tid];
    gp = wave64_sum(gp);
    if (tid == 0) S->lgz = gp + gate_b[0];
  }
  __syncthreads();

  int m = ln & 15, q = ln >> 4;
  float gz = S->lgz;
  int mb = blockIdx.x - NB_EDGE;

  for (int it = 0; it < TILES_PER_BLOCK; ++it) {
    int rowbase = (mb*TILES_PER_BLOCK + it)*64 + w*16;
    const float* arow = base + (size_t)(rowbase + m)*H;

    f32x4 a0 = *(const f32x4*)(arow + q*8);
    f32x4 a1 = *(const f32x4*)(arow + q*8 + 4);
    f32x4 a2 = *(const f32x4*)(arow + 32 + q*8);
    f32x4 a3 = *(const f32x4*)(arow + 32 + q*8 + 4);

    // gate logit: base . gate_W_top (reduce across q groups)
    float gp = 0.f;
    #pragma unroll
    for (int j = 0; j < 4; ++j) {
      gp += a0[j]*S->lgw[q*8+j]    + a1[j]*S->lgw[q*8+4+j];
      gp += a2[j]*S->lgw[32+q*8+j] + a3[j]*S->lgw[32+q*8+4+j];
    }
    gp += __shfl_xor(gp, 16, 64);
    gp += __shfl_xor(gp, 32, 64);
    float g = 1.0f / (1.0f + __expf(-(gp + gz)));
    if (q == 0) S->lg[w][m] = g;        // per-wave buffer, no barrier needed

    // A fragments (lane: row m, k = q*8+j)
    s16x8 A0, A1;
    #pragma unroll
    for (int j = 0; j < 4; ++j) {
      A0[j]   = (short)f2bf(a0[j]);
      A0[j+4] = (short)f2bf(a1[j]);
      A1[j]   = (short)f2bf(a2[j]);
      A1[j+4] = (short)f2bf(a3[j]);
    }

    // hidden = relu(base @ W1_top + c1z)   (c1z folded into C-init)
    f32x4 hacc[4];
    #pragma unroll
    for (int ct = 0; ct < 4; ++ct) {
      const s16x8 B0 = *(const s16x8*)&S->lw1[(ct*16 + m)*72 + q*8];
      const s16x8 B1 = *(const s16x8*)&S->lw1[(ct*16 + m)*72 + 32 + q*8];
      float c1v = S->lc1[ct*16 + m];
      f32x4 c = {c1v, c1v, c1v, c1v};
      c = __builtin_amdgcn_mfma_f32_16x16x32_bf16(A0, B0, c, 0, 0, 0);
      hacc[ct] = __builtin_amdgcn_mfma_f32_16x16x32_bf16(A1, B1, c, 0, 0, 0);
    }
    // D layout: col = ct*16+m, row = q*4+r  -> per-wave LDS round trip
    #pragma unroll
    for (int ct = 0; ct < 4; ++ct) {
      #pragma unroll
      for (int r = 0; r < 4; ++r) {
        float v = fmaxf(hacc[ct][r], 0.f);
        S->scratch[w].h[(q*4 + r)*72 + ct*16 + m] = f2bf(v);
      }
    }
    // same-wave write->read: compiler inserts lgkmcnt wait; no __syncthreads
    s16x8 HA0 = *(const s16x8*)&S->scratch[w].h[m*72 + q*8];
    s16x8 HA1 = *(const s16x8*)&S->scratch[w].h[m*72 + 32 + q*8];

    // fused = hidden @ W2 + fus_b2   (bias folded into C-init)
    f32x4 facc[4];
    #pragma unroll
    for (int ct = 0; ct < 4; ++ct) {
      const s16x8 B0 = *(const s16x8*)&S->lw2[(ct*16 + m)*72 + q*8];
      const s16x8 B1 = *(const s16x8*)&S->lw2[(ct*16 + m)*72 + 32 + q*8];
      float b2v = S->lb2[ct*16 + m];
      f32x4 c = {b2v, b2v, b2v, b2v};
      c = __builtin_amdgcn_mfma_f32_16x16x32_bf16(HA0, B0, c, 0, 0, 0);
      facc[ct] = __builtin_amdgcn_mfma_f32_16x16x32_bf16(HA1, B1, c, 0, 0, 0);
    }

    // --- vectorized epilogue: transpose facc through per-wave LDS ---------
    // writer lane (q,m): facc[ct][r] = fused[local row q*4+r][col ct*16+m]
    #pragma unroll
    for (int ct = 0; ct < 4; ++ct) {
      #pragma unroll
      for (int r = 0; r < 4; ++r)
        S->scratch[w].x[(q*4 + r)*68 + ct*16 + m] = facc[ct][r];
    }
    // reader lane (q,m): local row m, cols q*16..q*16+15 (same-wave, no barrier)
    f32x4 f0 = *(const f32x4*)&S->scratch[w].x[m*68 + q*16];
    f32x4 f1 = *(const f32x4*)&S->scratch[w].x[m*68 + q*16 + 4];
    f32x4 f2 = *(const f32x4*)&S->scratch[w].x[m*68 + q*16 + 8];
    f32x4 f3 = *(const f32x4*)&S->scratch[w].x[m*68 + q*16 + 12];

    float gr = S->lg[w][m];             // gate for row m (written by lane q==0)

    const float* brow = base + (size_t)(rowbase + m)*H + q*16;
    f32x4 b0 = *(const f32x4*)(brow);
    f32x4 b1 = *(const f32x4*)(brow + 4);
    f32x4 b2 = *(const f32x4*)(brow + 8);
    f32x4 b3 = *(const f32x4*)(brow + 12);

    f32x4 o0, o1, o2, o3;
    #pragma unroll
    for (int j = 0; j < 4; ++j) {
      o0[j] = fmaf(gr, f0[j] - b0[j], b0[j]);
      o1[j] = fmaf(gr, f1[j] - b1[j], b1[j]);
      o2[j] = fmaf(gr, f2[j] - b2[j], b2[j]);
      o3[j] = fmaf(gr, f3[j] - b3[j], b3[j]);
    }
    float* orow = out + (size_t)(rowbase + m)*H + q*16;
    *(f32x4*)(orow)      = o0;
    *(f32x4*)(orow + 4)  = o1;
    *(f32x4*)(orow + 8)  = o2;
    *(f32x4*)(orow + 12) = o3;
  }
}

// ---------------------------------------------------------------------------
// fixup: overwrite the <=E touched rows per sample with their true prompt.
// Wave w handles edges w, w+4, ... ; weights staged in LDS; no barriers after.
// ---------------------------------------------------------------------------
__global__ __launch_bounds__(256) void fixup_kernel(
    const float* __restrict__ base,
    const float* __restrict__ fus_W1, const float* __restrict__ fus_b1,
    const float* __restrict__ fus_W2, const float* __restrict__ fus_b2,
    const float* __restrict__ gate_W, const float* __restrict__ gate_b,
    const int* __restrict__ trows, const float* __restrict__ tprompt,
    float* __restrict__ out)
{
  __shared__ float W1s[2*H*H];   // 32 KB
  __shared__ float W2s[H*H];     // 16 KB
  int b = blockIdx.x, tid = threadIdx.x, w = tid >> 6, ln = tid & 63;
  for (int i = tid; i < 2*H*H; i += 256) W1s[i] = fus_W1[i];
  for (int i = tid; i < H*H;   i += 256) W2s[i] = fus_W2[i];
  __syncthreads();
  float gb = gate_b[0];
  #pragma unroll
  for (int i = 0; i < E/4; ++i) {
    int e = w + i*4;
    int r = trows[b*E + e];
    if (r < 0) continue;
    float bv = base[((size_t)b*R + r)*H + ln];
    float pv = tprompt[(b*E + e)*H + ln];
    float acc = fus_b1[ln];
    #pragma unroll 8
    for (int k = 0; k < H; ++k)
      acc += __shfl(bv, k, 64)*W1s[k*H + ln] + __shfl(pv, k, 64)*W1s[(H+k)*H + ln];
    float h = fmaxf(acc, 0.f);
    float f = fus_b2[ln];
    #pragma unroll 8
    for (int k = 0; k < H; ++k)
      f += __shfl(h, k, 64)*W2s[k*H + ln];
    float gp = bv*gate_W[ln] + pv*gate_W[H + ln];
    gp = wave64_sum(gp);
    float g = 1.0f/(1.0f + __expf(-(gp + gb)));
    out[((size_t)b*R + r)*H + ln] = fmaf(g, f - bv, bv);
  }
}

// ---------------------------------------------------------------------------
extern "C" void kernel_launch(void* const* d_in, const int* in_sizes, int n_in,
                              void* d_out, int out_size, void* d_ws, size_t ws_size,
                              hipStream_t stream)
{
  const int*   qrel   = (const int*)d_in[0];
  const int*   etyp   = (const int*)d_in[1];
  const float* base   = (const float*)d_in[2];
  const float* noise  = (const float*)d_in[3];
  const float* msg_W  = (const float*)d_in[4];
  const float* msg_b  = (const float*)d_in[5];
  const float* upd_W  = (const float*)d_in[6];
  const float* upd_b  = (const float*)d_in[7];
  const float* ln_g   = (const float*)d_in[8];
  const float* ln_b   = (const float*)d_in[9];
  const float* fus_W1 = (const float*)d_in[10];
  const float* fus_b1 = (const float*)d_in[11];
  const float* fus_W2 = (const float*)d_in[12];
  const float* fus_b2 = (const float*)d_in[13];
  const float* gate_W = (const float*)d_in[14];
  const float* gate_b = (const float*)d_in[15];
  float* out = (float*)d_out;

  char* ws = (char*)d_ws;
  float* tprompt = (float*)ws;                       // B*E*H f32
  int*   trows   = (int*)(ws + (size_t)B*E*H*4);     // B*E int

  fused_kernel<<<NB_EDGE + NB_MAIN, 256, 0, stream>>>(
      qrel, etyp, base, noise, msg_W, msg_b, upd_W, upd_b, ln_g, ln_b,
      fus_W1, fus_b1, fus_W2, fus_b2, gate_W, gate_b,
      trows, tprompt, out);
  fixup_kernel<<<B, 256, 0, stream>>>(base, fus_W1, fus_b1, fus_W2, fus_b2,
                                      gate_W, gate_b, trows, tprompt, out);
}

// Round 3
// 358.671 us; speedup vs baseline: 1.0564x; 1.0564x over previous
//
#include <hip/hip_runtime.h>

#define B 256
#define R 2048
#define H 64
#define E 20
#define LN_EPS 1e-5f

#define NB_EDGE 256
#define NB_MAIN 1024
#define TILES_PER_BLOCK 8   // NB_MAIN * TILES_PER_BLOCK * 64 == B*R

typedef float f32x4 __attribute__((ext_vector_type(4)));
typedef short s16x8 __attribute__((ext_vector_type(8)));

__device__ __forceinline__ unsigned short f2bf(float x){
  unsigned int u = __float_as_uint(x);
  u += 0x7fffu + ((u >> 16) & 1u);   // round-to-nearest-even
  return (unsigned short)(u >> 16);
}

__device__ __forceinline__ float wave64_sum(float v){
  #pragma unroll
  for (int m = 1; m < 64; m <<= 1) v += __shfl_xor(v, m, 64);
  return v;
}

// ---------------------------------------------------------------------------
// LDS layouts (union: edge blocks vs main blocks)
// ---------------------------------------------------------------------------
struct MainS {
  unsigned short lw1[H*72];        // W1_top transposed [n][k], bf16, pad 72
  unsigned short lw2[H*72];        // W2 transposed    [n][k], bf16, pad 72
  unsigned short lhid[4][16*72];   // per-wave hidden tile (bf16)
  float lc1[H];                    // prompt_zero @ W1_bot + fus_b1
  float lb2[H];
  float lgw[H];                    // gate_W top half
  float lgz;                       // prompt_zero . gate_W_bot + gate_b
};
struct EdgeS {
  float wsum[H*H];                 // msg_W top + bottom halves
  float msgbuf[E][H];
  int   et[E];
};
union SMem { MainS m; EdgeS e; };

// ---------------------------------------------------------------------------
// fused kernel: blocks [0,NB_EDGE) = per-sample prompt encoder (sparse rows),
//               blocks [NB_EDGE, NB_EDGE+NB_MAIN) = dense main path.
// ---------------------------------------------------------------------------
__global__ __launch_bounds__(256) void fused_kernel(
    const int* __restrict__ qrel, const int* __restrict__ etype,
    const float* __restrict__ base, const float* __restrict__ noise,
    const float* __restrict__ msg_W, const float* __restrict__ msg_b,
    const float* __restrict__ upd_W, const float* __restrict__ upd_b,
    const float* __restrict__ ln_g,  const float* __restrict__ ln_b,
    const float* __restrict__ fus_W1,const float* __restrict__ fus_b1,
    const float* __restrict__ fus_W2,const float* __restrict__ fus_b2,
    const float* __restrict__ gate_W,const float* __restrict__ gate_b,
    int* __restrict__ trows, float* __restrict__ tprompt,
    float* __restrict__ out)
{
  __shared__ SMem smem;
  int tid = threadIdx.x;
  int w = tid >> 6, ln = tid & 63;

  if (blockIdx.x < NB_EDGE) {
    // ------------------------------ EDGE PATH ------------------------------
    EdgeS* S = &smem.e;
    int b = blockIdx.x;
    if (tid < E) S->et[tid] = etype[b*E + tid];
    for (int i = tid; i < H*H; i += 256)
      S->wsum[i] = msg_W[i] + msg_W[H*H + i];
    __syncthreads();
    int q = qrel[b];

    // phase B: messages (wave w handles e = w, w+4, ...)
    #pragma unroll
    for (int i = 0; i < E/4; ++i) {
      int e = w + i*4;
      int r = S->et[e];
      float hv = (r == q) ? 1.0f : noise[((size_t)b*R + r)*H + ln] * 0.1f;
      float acc = msg_b[ln];
      #pragma unroll 8
      for (int k = 0; k < H; ++k)
        acc += __shfl(hv, k, 64) * S->wsum[k*H + ln];
      S->msgbuf[e][ln] = fmaxf(acc, 0.f);
    }
    __syncthreads();

    // phase C: dedup + aggregate + update-net + LN
    #pragma unroll
    for (int i = 0; i < E/4; ++i) {
      int e = w + i*4;
      int r = S->et[e];
      bool first = true;
      for (int e2 = 0; e2 < e; ++e2) if (S->et[e2] == r) first = false;
      if (!first) { if (ln == 0) trows[b*E + e] = -1; continue; }
      float agg = 0.f;
      for (int e2 = e; e2 < E; ++e2)
        if (S->et[e2] == r) agg += S->msgbuf[e2][ln];
      float u = upd_b[ln];
      #pragma unroll 8
      for (int k = 0; k < H; ++k)
        u += __shfl(agg, k, 64) * upd_W[k*H + ln];
      float mu = wave64_sum(u) * (1.0f/H);
      float d  = u - mu;
      float var= wave64_sum(d*d) * (1.0f/H);
      float p  = d * rsqrtf(var + LN_EPS) * ln_g[ln] + ln_b[ln];
      tprompt[(b*E + e)*H + ln] = p;
      if (ln == 0) trows[b*E + e] = r;
    }
    return;
  }

  // ------------------------------- MAIN PATH -------------------------------
  MainS* S = &smem.m;
  // stage: coalesced global read, transposed bf16 LDS write
  for (int i = tid; i < H*H; i += 256) {
    int k = i >> 6, n = i & 63;
    S->lw1[n*72 + k] = f2bf(fus_W1[i]);   // top half of fus_W1
    S->lw2[n*72 + k] = f2bf(fus_W2[i]);
  }
  if (tid < H) {
    S->lb2[tid] = fus_b2[tid];
    S->lgw[tid] = gate_W[tid];
  }
  if (tid < 64) {          // wave 0: prompt_zero, c1z, gz
    float u  = upd_b[tid];
    float mu = wave64_sum(u) * (1.0f/H);
    float d  = u - mu;
    float var= wave64_sum(d*d) * (1.0f/H);
    float p  = d * rsqrtf(var + LN_EPS) * ln_g[tid] + ln_b[tid];
    float acc = fus_b1[tid];
    #pragma unroll 8
    for (int k = 0; k < H; ++k)
      acc += __shfl(p, k, 64) * fus_W1[(H+k)*H + tid];
    S->lc1[tid] = acc;
    float gp = p * gate_W[H + tid];
    gp = wave64_sum(gp);
    if (tid == 0) S->lgz = gp + gate_b[0];
  }
  __syncthreads();

  int m = ln & 15, q = ln >> 4;
  float gz = S->lgz;
  int mb = blockIdx.x - NB_EDGE;

  for (int it = 0; it < TILES_PER_BLOCK; ++it) {
    int rowbase = (mb*TILES_PER_BLOCK + it)*64 + w*16;
    const float* arow = base + (size_t)(rowbase + m)*H;

    f32x4 a0 = *(const f32x4*)(arow + q*8);
    f32x4 a1 = *(const f32x4*)(arow + q*8 + 4);
    f32x4 a2 = *(const f32x4*)(arow + 32 + q*8);
    f32x4 a3 = *(const f32x4*)(arow + 32 + q*8 + 4);

    // gate logit: base . gate_W_top (reduce across q groups)
    // after the two xor-reduces ALL lanes hold the full row-m dot product.
    float gp = 0.f;
    #pragma unroll
    for (int j = 0; j < 4; ++j) {
      gp += a0[j]*S->lgw[q*8+j]    + a1[j]*S->lgw[q*8+4+j];
      gp += a2[j]*S->lgw[32+q*8+j] + a3[j]*S->lgw[32+q*8+4+j];
    }
    gp += __shfl_xor(gp, 16, 64);
    gp += __shfl_xor(gp, 32, 64);
    float g = 1.0f / (1.0f + __expf(-(gp + gz)));   // gate for row m, in-register

    // A fragments (lane: row m, k = q*8+j)
    s16x8 A0, A1;
    #pragma unroll
    for (int j = 0; j < 4; ++j) {
      A0[j]   = (short)f2bf(a0[j]);
      A0[j+4] = (short)f2bf(a1[j]);
      A1[j]   = (short)f2bf(a2[j]);
      A1[j+4] = (short)f2bf(a3[j]);
    }

    // hidden = relu(base @ W1_top + c1z)   (c1z folded into C-init)
    f32x4 hacc[4];
    #pragma unroll
    for (int ct = 0; ct < 4; ++ct) {
      const s16x8 B0 = *(const s16x8*)&S->lw1[(ct*16 + m)*72 + q*8];
      const s16x8 B1 = *(const s16x8*)&S->lw1[(ct*16 + m)*72 + 32 + q*8];
      float c1v = S->lc1[ct*16 + m];
      f32x4 c = {c1v, c1v, c1v, c1v};
      c = __builtin_amdgcn_mfma_f32_16x16x32_bf16(A0, B0, c, 0, 0, 0);
      hacc[ct] = __builtin_amdgcn_mfma_f32_16x16x32_bf16(A1, B1, c, 0, 0, 0);
    }
    // D layout: col = ct*16+m, row = q*4+r  -> per-wave LDS round trip
    #pragma unroll
    for (int ct = 0; ct < 4; ++ct) {
      #pragma unroll
      for (int r = 0; r < 4; ++r) {
        float v = fmaxf(hacc[ct][r], 0.f);
        S->lhid[w][(q*4 + r)*72 + ct*16 + m] = f2bf(v);
      }
    }
    // same-wave write->read: compiler inserts lgkmcnt wait; no __syncthreads
    s16x8 HA0 = *(const s16x8*)&S->lhid[w][m*72 + q*8];
    s16x8 HA1 = *(const s16x8*)&S->lhid[w][m*72 + 32 + q*8];

    // fused^T = W2^T @ hidden^T  (operand swap):
    //   A' = W2^T fragment == our existing lw2 B-read
    //   B' = hidden^T fragment == our existing HA read
    //   D' lane (m,q), tile ct, reg r = F[row m][col ct*16 + q*4 + r]
    //   C-init = fus_b2[ct*16 + q*4 .. +3]  (vector LDS read)
    f32x4 facc[4];
    #pragma unroll
    for (int ct = 0; ct < 4; ++ct) {
      const s16x8 B0 = *(const s16x8*)&S->lw2[(ct*16 + m)*72 + q*8];
      const s16x8 B1 = *(const s16x8*)&S->lw2[(ct*16 + m)*72 + 32 + q*8];
      f32x4 c = *(const f32x4*)&S->lb2[ct*16 + q*4];
      c = __builtin_amdgcn_mfma_f32_16x16x32_bf16(B0, HA0, c, 0, 0, 0);
      facc[ct] = __builtin_amdgcn_mfma_f32_16x16x32_bf16(B1, HA1, c, 0, 0, 0);
    }

    // epilogue: row-major f32x4 output directly from facc
    const float* brow = base + (size_t)(rowbase + m)*H;
    float*       orow = out  + (size_t)(rowbase + m)*H;
    #pragma unroll
    for (int ct = 0; ct < 4; ++ct) {
      int col = ct*16 + q*4;
      f32x4 bv = *(const f32x4*)(brow + col);
      f32x4 o;
      #pragma unroll
      for (int j = 0; j < 4; ++j)
        o[j] = fmaf(g, facc[ct][j] - bv[j], bv[j]);
      *(f32x4*)(orow + col) = o;
    }
  }
}

// ---------------------------------------------------------------------------
// fixup: overwrite the <=E touched rows per sample with their true prompt.
// Wave w handles edges w, w+4, ... ; weights staged in LDS; no barriers after.
// ---------------------------------------------------------------------------
__global__ __launch_bounds__(256) void fixup_kernel(
    const float* __restrict__ base,
    const float* __restrict__ fus_W1, const float* __restrict__ fus_b1,
    const float* __restrict__ fus_W2, const float* __restrict__ fus_b2,
    const float* __restrict__ gate_W, const float* __restrict__ gate_b,
    const int* __restrict__ trows, const float* __restrict__ tprompt,
    float* __restrict__ out)
{
  __shared__ float W1s[2*H*H];   // 32 KB
  __shared__ float W2s[H*H];     // 16 KB
  int b = blockIdx.x, tid = threadIdx.x, w = tid >> 6, ln = tid & 63;
  for (int i = tid; i < 2*H*H; i += 256) W1s[i] = fus_W1[i];
  for (int i = tid; i < H*H;   i += 256) W2s[i] = fus_W2[i];
  __syncthreads();
  float gb = gate_b[0];
  #pragma unroll
  for (int i = 0; i < E/4; ++i) {
    int e = w + i*4;
    int r = trows[b*E + e];
    if (r < 0) continue;
    float bv = base[((size_t)b*R + r)*H + ln];
    float pv = tprompt[(b*E + e)*H + ln];
    float acc = fus_b1[ln];
    #pragma unroll 8
    for (int k = 0; k < H; ++k)
      acc += __shfl(bv, k, 64)*W1s[k*H + ln] + __shfl(pv, k, 64)*W1s[(H+k)*H + ln];
    float h = fmaxf(acc, 0.f);
    float f = fus_b2[ln];
    #pragma unroll 8
    for (int k = 0; k < H; ++k)
      f += __shfl(h, k, 64)*W2s[k*H + ln];
    float gp = bv*gate_W[ln] + pv*gate_W[H + ln];
    gp = wave64_sum(gp);
    float g = 1.0f/(1.0f + __expf(-(gp + gb)));
    out[((size_t)b*R + r)*H + ln] = fmaf(g, f - bv, bv);
  }
}

// ---------------------------------------------------------------------------
extern "C" void kernel_launch(void* const* d_in, const int* in_sizes, int n_in,
                              void* d_out, int out_size, void* d_ws, size_t ws_size,
                              hipStream_t stream)
{
  const int*   qrel   = (const int*)d_in[0];
  const int*   etyp   = (const int*)d_in[1];
  const float* base   = (const float*)d_in[2];
  const float* noise  = (const float*)d_in[3];
  const float* msg_W  = (const float*)d_in[4];
  const float* msg_b  = (const float*)d_in[5];
  const float* upd_W  = (const float*)d_in[6];
  const float* upd_b  = (const float*)d_in[7];
  const float* ln_g   = (const float*)d_in[8];
  const float* ln_b   = (const float*)d_in[9];
  const float* fus_W1 = (const float*)d_in[10];
  const float* fus_b1 = (const float*)d_in[11];
  const float* fus_W2 = (const float*)d_in[12];
  const float* fus_b2 = (const float*)d_in[13];
  const float* gate_W = (const float*)d_in[14];
  const float* gate_b = (const float*)d_in[15];
  float* out = (float*)d_out;

  char* ws = (char*)d_ws;
  float* tprompt = (float*)ws;                       // B*E*H f32
  int*   trows   = (int*)(ws + (size_t)B*E*H*4);     // B*E int

  fused_kernel<<<NB_EDGE + NB_MAIN, 256, 0, stream>>>(
      qrel, etyp, base, noise, msg_W, msg_b, upd_W, upd_b, ln_g, ln_b,
      fus_W1, fus_b1, fus_W2, fus_b2, gate_W, gate_b,
      trows, tprompt, out);
  fixup_kernel<<<B, 256, 0, stream>>>(base, fus_W1, fus_b1, fus_W2, fus_b2,
                                      gate_W, gate_b, trows, tprompt, out);
}